// Round 3
// baseline (232.617 us; speedup 1.0000x reference)
//
#include <hip/hip_runtime.h>

namespace {
constexpr int A_N = 96;
constexpr int U_N = 128;
constexpr int V_N = 128;
constexpr int W_N = 128;
constexpr int H_N = 128;
constexpr int NSTEPS = 128;
constexpr float T_HALF = 89.80256121069154f;
constexpr float DT = 1.4031650189170554f;  // 2*T/NSTEPS
constexpr int RAYS_PER_BLOCK = 16;         // ZT=8: 16 lanes/ray, 16 rays/block
constexpr int SEGS = 4;                    // t-range split for TLP
constexpr int STEPS_PER_SEG = NSTEPS / SEGS;
}

__global__ __launch_bounds__(256) void joseph_fwd(
    const float* __restrict__ vol,      // (W,H,D) row-major: vol[x*H*D + y*D + z]
    const float* __restrict__ angles,   // (A)
    float* __restrict__ out)            // (U,A,V) row-major, pre-zeroed
{
    const int zo  = threadIdx.x & 15;   // 16 groups of 8 z-values = 128 z
    const int r   = threadIdx.x >> 4;   // ray within block (0..15)
    const int u_i = blockIdx.x * RAYS_PER_BLOCK + r;
    const int a   = blockIdx.y;
    const int seg = blockIdx.z;

    const float ang = angles[a];
    const float c = cosf(ang);
    const float s = sinf(ang);
    const float u = (float)u_i - 63.5f;
    // x_idx = -u*sin + t*cos + 63.5 ;  y_idx = u*cos + t*sin + 63.5
    const float xb = fmaf(-u, s, 63.5f);
    const float yb = fmaf( u, c, 63.5f);

    const float* volz = vol + 8 * zo;   // this lane's z offset (8 contiguous floats)
    float4 accA = make_float4(0.f, 0.f, 0.f, 0.f);
    float4 accB = make_float4(0.f, 0.f, 0.f, 0.f);

    const int i0 = seg * STEPS_PER_SEG;
    const int i1 = i0 + STEPS_PER_SEG;

    for (int i = i0; i < i1; ++i) {
        const float t  = fmaf((float)i + 0.5f, DT, -T_HALF);
        const float xi = fmaf(t, c, xb);
        const float yi = fmaf(t, s, yb);

        const float fx0f = floorf(xi);
        const float fy0f = floorf(yi);
        const int x0 = (int)fx0f;
        const int y0 = (int)fy0f;
        const float fx = xi - fx0f;
        const float fy = yi - fy0f;
        const int x1 = x0 + 1;
        const int y1 = y0 + 1;

        const float wx0 = (x0 >= 0 && x0 < W_N) ? (1.f - fx) : 0.f;
        const float wx1 = (x1 >= 0 && x1 < W_N) ? fx : 0.f;
        const float wy0 = (y0 >= 0 && y0 < H_N) ? (1.f - fy) : 0.f;
        const float wy1 = (y1 >= 0 && y1 < H_N) ? fy : 0.f;

        // zero-padding: fully-outside sample contributes 0
        if ((wx0 + wx1) == 0.f || (wy0 + wy1) == 0.f) continue;

        const int cx0 = min(max(x0, 0), W_N - 1);
        const int cx1 = min(max(x1, 0), W_N - 1);
        const int cy0 = min(max(y0, 0), H_N - 1);
        const int cy1 = min(max(y1, 0), H_N - 1);

        const float* p00 = volz + ((cx0 * H_N + cy0) << 7);
        const float* p01 = volz + ((cx1 * H_N + cy0) << 7);
        const float* p10 = volz + ((cx0 * H_N + cy1) << 7);
        const float* p11 = volz + ((cx1 * H_N + cy1) << 7);

        const float4 v00a = *(const float4*)(p00);
        const float4 v00b = *(const float4*)(p00 + 4);
        const float4 v01a = *(const float4*)(p01);
        const float4 v01b = *(const float4*)(p01 + 4);
        const float4 v10a = *(const float4*)(p10);
        const float4 v10b = *(const float4*)(p10 + 4);
        const float4 v11a = *(const float4*)(p11);
        const float4 v11b = *(const float4*)(p11 + 4);

        const float w00 = wx0 * wy0;
        const float w01 = wx1 * wy0;
        const float w10 = wx0 * wy1;
        const float w11 = wx1 * wy1;

        accA.x = fmaf(w00, v00a.x, fmaf(w01, v01a.x, fmaf(w10, v10a.x, fmaf(w11, v11a.x, accA.x))));
        accA.y = fmaf(w00, v00a.y, fmaf(w01, v01a.y, fmaf(w10, v10a.y, fmaf(w11, v11a.y, accA.y))));
        accA.z = fmaf(w00, v00a.z, fmaf(w01, v01a.z, fmaf(w10, v10a.z, fmaf(w11, v11a.z, accA.z))));
        accA.w = fmaf(w00, v00a.w, fmaf(w01, v01a.w, fmaf(w10, v10a.w, fmaf(w11, v11a.w, accA.w))));
        accB.x = fmaf(w00, v00b.x, fmaf(w01, v01b.x, fmaf(w10, v10b.x, fmaf(w11, v11b.x, accB.x))));
        accB.y = fmaf(w00, v00b.y, fmaf(w01, v01b.y, fmaf(w10, v10b.y, fmaf(w11, v11b.y, accB.y))));
        accB.z = fmaf(w00, v00b.z, fmaf(w01, v01b.z, fmaf(w10, v10b.z, fmaf(w11, v11b.z, accB.z))));
        accB.w = fmaf(w00, v00b.w, fmaf(w01, v01b.w, fmaf(w10, v10b.w, fmaf(w11, v11b.w, accB.w))));
    }

    float* op = out + (u_i * A_N + a) * V_N + 8 * zo;
    atomicAdd(op + 0, accA.x * DT);
    atomicAdd(op + 1, accA.y * DT);
    atomicAdd(op + 2, accA.z * DT);
    atomicAdd(op + 3, accA.w * DT);
    atomicAdd(op + 4, accB.x * DT);
    atomicAdd(op + 5, accB.y * DT);
    atomicAdd(op + 6, accB.z * DT);
    atomicAdd(op + 7, accB.w * DT);
}

extern "C" void kernel_launch(void* const* d_in, const int* in_sizes, int n_in,
                              void* d_out, int out_size, void* d_ws, size_t ws_size,
                              hipStream_t stream) {
    const float* vol    = (const float*)d_in[0];
    const float* angles = (const float*)d_in[1];
    float* out          = (float*)d_out;

    hipMemsetAsync(out, 0, (size_t)out_size * sizeof(float), stream);

    dim3 grid(U_N / RAYS_PER_BLOCK, A_N, SEGS);  // 8 x 96 x 4 = 3072 blocks
    dim3 block(256);
    hipLaunchKernelGGL(joseph_fwd, grid, block, 0, stream, vol, angles, out);
}

// Round 4
// 135.277 us; speedup vs baseline: 1.7196x; 1.7196x over previous
//
#include <hip/hip_runtime.h>

namespace {
constexpr int A_N = 96;
constexpr int U_N = 128;
constexpr int V_N = 128;
constexpr int W_N = 128;
constexpr int H_N = 128;
constexpr int NSTEPS = 128;
constexpr float T_HALF = 89.80256121069154f;
constexpr float DT = 1.4031650189170554f;  // 2*T/NSTEPS
constexpr int RAYS_PER_BLOCK = 16;         // ZT=8: 16 lanes/ray, 16 rays/block
constexpr size_t VOL_ELEMS = (size_t)W_N * H_N * V_N;  // 2M
}

// ---- pre-pass: fp32 volume -> bf16 (round-to-nearest-even), packed pairs ----
__device__ __forceinline__ unsigned int f2bf(float f) {
    unsigned int u = __float_as_uint(f);
    return (u + 0x7FFFu + ((u >> 16) & 1u)) >> 16;
}

__global__ __launch_bounds__(256) void vol_to_bf16(
    const float* __restrict__ vol, unsigned int* __restrict__ volb /* 2 bf16 per uint */)
{
    const int i = blockIdx.x * blockDim.x + threadIdx.x;   // one uint4 (8 floats) per thread
    const float4 f0 = *(const float4*)(vol + 8 * (size_t)i);
    const float4 f1 = *(const float4*)(vol + 8 * (size_t)i + 4);
    uint4 o;
    o.x = f2bf(f0.x) | (f2bf(f0.y) << 16);
    o.y = f2bf(f0.z) | (f2bf(f0.w) << 16);
    o.z = f2bf(f1.x) | (f2bf(f1.y) << 16);
    o.w = f2bf(f1.z) | (f2bf(f1.w) << 16);
    *(uint4*)(volb + 4 * (size_t)i) = o;
}

// ---- main projector, bf16 volume ----
__device__ __forceinline__ void fma8(const uint4 w, float wt, float4& A, float4& B) {
    A.x = fmaf(wt, __uint_as_float(w.x << 16),        A.x);
    A.y = fmaf(wt, __uint_as_float(w.x & 0xFFFF0000u), A.y);
    A.z = fmaf(wt, __uint_as_float(w.y << 16),        A.z);
    A.w = fmaf(wt, __uint_as_float(w.y & 0xFFFF0000u), A.w);
    B.x = fmaf(wt, __uint_as_float(w.z << 16),        B.x);
    B.y = fmaf(wt, __uint_as_float(w.z & 0xFFFF0000u), B.y);
    B.z = fmaf(wt, __uint_as_float(w.w << 16),        B.z);
    B.w = fmaf(wt, __uint_as_float(w.w & 0xFFFF0000u), B.w);
}

__global__ __launch_bounds__(256) void joseph_fwd_bf16(
    const unsigned short* __restrict__ volb,  // (W,H,D) bf16
    const float* __restrict__ angles,
    float* __restrict__ out)                  // (U,A,V)
{
    const int zo  = threadIdx.x & 15;   // 16 groups of 8 z-values
    const int r   = threadIdx.x >> 4;
    const int u_i = blockIdx.x * RAYS_PER_BLOCK + r;
    const int a   = blockIdx.y;

    const float ang = angles[a];
    const float c = cosf(ang);
    const float s = sinf(ang);
    const float u = (float)u_i - 63.5f;
    const float xb = fmaf(-u, s, 63.5f);
    const float yb = fmaf( u, c, 63.5f);

    const unsigned short* volz = volb + 8 * zo;
    float4 accA = make_float4(0.f, 0.f, 0.f, 0.f);
    float4 accB = make_float4(0.f, 0.f, 0.f, 0.f);

    for (int i = 0; i < NSTEPS; ++i) {
        const float t  = fmaf((float)i + 0.5f, DT, -T_HALF);
        const float xi = fmaf(t, c, xb);
        const float yi = fmaf(t, s, yb);

        const float fx0f = floorf(xi);
        const float fy0f = floorf(yi);
        const int x0 = (int)fx0f;
        const int y0 = (int)fy0f;
        const float fx = xi - fx0f;
        const float fy = yi - fy0f;
        const int x1 = x0 + 1;
        const int y1 = y0 + 1;

        const float wx0 = (x0 >= 0 && x0 < W_N) ? (1.f - fx) : 0.f;
        const float wx1 = (x1 >= 0 && x1 < W_N) ? fx : 0.f;
        const float wy0 = (y0 >= 0 && y0 < H_N) ? (1.f - fy) : 0.f;
        const float wy1 = (y1 >= 0 && y1 < H_N) ? fy : 0.f;

        if ((wx0 + wx1) == 0.f || (wy0 + wy1) == 0.f) continue;

        const int cx0 = min(max(x0, 0), W_N - 1);
        const int cx1 = min(max(x1, 0), W_N - 1);
        const int cy0 = min(max(y0, 0), H_N - 1);
        const int cy1 = min(max(y1, 0), H_N - 1);

        const uint4 v00 = *(const uint4*)(volz + ((cx0 * H_N + cy0) << 7));
        const uint4 v01 = *(const uint4*)(volz + ((cx1 * H_N + cy0) << 7));
        const uint4 v10 = *(const uint4*)(volz + ((cx0 * H_N + cy1) << 7));
        const uint4 v11 = *(const uint4*)(volz + ((cx1 * H_N + cy1) << 7));

        fma8(v00, wx0 * wy0, accA, accB);
        fma8(v01, wx1 * wy0, accA, accB);
        fma8(v10, wx0 * wy1, accA, accB);
        fma8(v11, wx1 * wy1, accA, accB);
    }

    float* op = out + (u_i * A_N + a) * V_N + 8 * zo;
    *(float4*)(op)     = make_float4(accA.x * DT, accA.y * DT, accA.z * DT, accA.w * DT);
    *(float4*)(op + 4) = make_float4(accB.x * DT, accB.y * DT, accB.z * DT, accB.w * DT);
}

// ---- fallback: fp32 volume (used only if ws too small; R2 structure) ----
__global__ __launch_bounds__(256) void joseph_fwd_f32(
    const float* __restrict__ vol,
    const float* __restrict__ angles,
    float* __restrict__ out)
{
    const int zo  = threadIdx.x & 15;
    const int r   = threadIdx.x >> 4;
    const int u_i = blockIdx.x * RAYS_PER_BLOCK + r;
    const int a   = blockIdx.y;

    const float ang = angles[a];
    const float c = cosf(ang);
    const float s = sinf(ang);
    const float u = (float)u_i - 63.5f;
    const float xb = fmaf(-u, s, 63.5f);
    const float yb = fmaf( u, c, 63.5f);

    const float* volz = vol + 8 * zo;
    float4 accA = make_float4(0.f, 0.f, 0.f, 0.f);
    float4 accB = make_float4(0.f, 0.f, 0.f, 0.f);

    for (int i = 0; i < NSTEPS; ++i) {
        const float t  = fmaf((float)i + 0.5f, DT, -T_HALF);
        const float xi = fmaf(t, c, xb);
        const float yi = fmaf(t, s, yb);
        const float fx0f = floorf(xi);
        const float fy0f = floorf(yi);
        const int x0 = (int)fx0f;
        const int y0 = (int)fy0f;
        const float fx = xi - fx0f;
        const float fy = yi - fy0f;
        const int x1 = x0 + 1;
        const int y1 = y0 + 1;
        const float wx0 = (x0 >= 0 && x0 < W_N) ? (1.f - fx) : 0.f;
        const float wx1 = (x1 >= 0 && x1 < W_N) ? fx : 0.f;
        const float wy0 = (y0 >= 0 && y0 < H_N) ? (1.f - fy) : 0.f;
        const float wy1 = (y1 >= 0 && y1 < H_N) ? fy : 0.f;
        if ((wx0 + wx1) == 0.f || (wy0 + wy1) == 0.f) continue;
        const int cx0 = min(max(x0, 0), W_N - 1);
        const int cx1 = min(max(x1, 0), W_N - 1);
        const int cy0 = min(max(y0, 0), H_N - 1);
        const int cy1 = min(max(y1, 0), H_N - 1);
        const float* p00 = volz + ((cx0 * H_N + cy0) << 7);
        const float* p01 = volz + ((cx1 * H_N + cy0) << 7);
        const float* p10 = volz + ((cx0 * H_N + cy1) << 7);
        const float* p11 = volz + ((cx1 * H_N + cy1) << 7);
        const float4 v00a = *(const float4*)(p00);
        const float4 v00b = *(const float4*)(p00 + 4);
        const float4 v01a = *(const float4*)(p01);
        const float4 v01b = *(const float4*)(p01 + 4);
        const float4 v10a = *(const float4*)(p10);
        const float4 v10b = *(const float4*)(p10 + 4);
        const float4 v11a = *(const float4*)(p11);
        const float4 v11b = *(const float4*)(p11 + 4);
        const float w00 = wx0 * wy0, w01 = wx1 * wy0, w10 = wx0 * wy1, w11 = wx1 * wy1;
        accA.x = fmaf(w00, v00a.x, fmaf(w01, v01a.x, fmaf(w10, v10a.x, fmaf(w11, v11a.x, accA.x))));
        accA.y = fmaf(w00, v00a.y, fmaf(w01, v01a.y, fmaf(w10, v10a.y, fmaf(w11, v11a.y, accA.y))));
        accA.z = fmaf(w00, v00a.z, fmaf(w01, v01a.z, fmaf(w10, v10a.z, fmaf(w11, v11a.z, accA.z))));
        accA.w = fmaf(w00, v00a.w, fmaf(w01, v01a.w, fmaf(w10, v10a.w, fmaf(w11, v11a.w, accA.w))));
        accB.x = fmaf(w00, v00b.x, fmaf(w01, v01b.x, fmaf(w10, v10b.x, fmaf(w11, v11b.x, accB.x))));
        accB.y = fmaf(w00, v00b.y, fmaf(w01, v01b.y, fmaf(w10, v10b.y, fmaf(w11, v11b.y, accB.y))));
        accB.z = fmaf(w00, v00b.z, fmaf(w01, v01b.z, fmaf(w10, v10b.z, fmaf(w11, v11b.z, accB.z))));
        accB.w = fmaf(w00, v00b.w, fmaf(w01, v01b.w, fmaf(w10, v10b.w, fmaf(w11, v11b.w, accB.w))));
    }

    float* op = out + (u_i * A_N + a) * V_N + 8 * zo;
    *(float4*)(op)     = make_float4(accA.x * DT, accA.y * DT, accA.z * DT, accA.w * DT);
    *(float4*)(op + 4) = make_float4(accB.x * DT, accB.y * DT, accB.z * DT, accB.w * DT);
}

extern "C" void kernel_launch(void* const* d_in, const int* in_sizes, int n_in,
                              void* d_out, int out_size, void* d_ws, size_t ws_size,
                              hipStream_t stream) {
    const float* vol    = (const float*)d_in[0];
    const float* angles = (const float*)d_in[1];
    float* out          = (float*)d_out;

    dim3 grid(U_N / RAYS_PER_BLOCK, A_N);   // 8 x 96 = 768 blocks
    dim3 block(256);

    if (ws_size >= VOL_ELEMS * sizeof(unsigned short)) {
        unsigned int* volb = (unsigned int*)d_ws;
        // 2M floats, 8 per thread -> 262144 threads = 1024 blocks
        hipLaunchKernelGGL(vol_to_bf16, dim3(VOL_ELEMS / 8 / 256), dim3(256), 0, stream,
                           vol, volb);
        hipLaunchKernelGGL(joseph_fwd_bf16, grid, block, 0, stream,
                           (const unsigned short*)volb, angles, out);
    } else {
        hipLaunchKernelGGL(joseph_fwd_f32, grid, block, 0, stream, vol, angles, out);
    }
}

// Round 5
// 118.925 us; speedup vs baseline: 1.9560x; 1.1375x over previous
//
#include <hip/hip_runtime.h>
#include <hip/hip_fp16.h>

namespace {
constexpr int A_N = 96;
constexpr int U_N = 128;
constexpr int V_N = 128;
constexpr int W_N = 128;
constexpr int H_N = 128;
constexpr int NSTEPS = 128;
constexpr float T_HALF = 89.80256121069154f;
constexpr float DT = 1.4031650189170554f;   // 2*T/NSTEPS
constexpr int RAYS_PER_BLOCK = 16;          // 16 lanes/ray (8 z each), 16 rays/block
constexpr int SEGS = 4;
constexpr size_t VOL_ELEMS = (size_t)W_N * H_N * V_N;             // 2M
constexpr size_t VOLH_BYTES = VOL_ELEMS * sizeof(unsigned short); // 4 MB
constexpr size_t SINO = (size_t)U_N * A_N * V_N;                  // 1.57M floats
}

// ---- pre-pass: fp32 volume -> f16 (rte), 8 values/thread ----
__device__ __forceinline__ unsigned int packh2(float a, float b) {
    return (unsigned int)__half_as_ushort(__float2half_rn(a)) |
           ((unsigned int)__half_as_ushort(__float2half_rn(b)) << 16);
}

__global__ __launch_bounds__(256) void vol_to_f16(
    const float* __restrict__ vol, unsigned int* __restrict__ volh)
{
    const size_t i = (size_t)blockIdx.x * 256 + threadIdx.x;
    const float4 f0 = *(const float4*)(vol + 8 * i);
    const float4 f1 = *(const float4*)(vol + 8 * i + 4);
    uint4 o;
    o.x = packh2(f0.x, f0.y);
    o.y = packh2(f0.z, f0.w);
    o.z = packh2(f1.x, f1.y);
    o.w = packh2(f1.z, f1.w);
    *(uint4*)(volh + 4 * i) = o;
}

// ---- projector: f16 volume, packed-half2 bilinear, fp32 accumulate ----
// dst: if gridDim.z==SEGS, partial buffers [seg][U][A][V] with scale=1;
//      if gridDim.z==1, final output with scale=DT.
__global__ __launch_bounds__(256) void joseph_fwd_f16(
    const unsigned short* __restrict__ volh,
    const float* __restrict__ angles,
    float* __restrict__ dst, float scale)
{
    const int zo  = threadIdx.x & 15;   // 16 groups of 8 z-values
    const int r   = threadIdx.x >> 4;
    const int u_i = blockIdx.x * RAYS_PER_BLOCK + r;
    const int a   = blockIdx.y;

    const float ang = angles[a];
    const float c = cosf(ang);
    const float s = sinf(ang);
    const float u = (float)u_i - 63.5f;
    const float xb = fmaf(-u, s, 63.5f);
    const float yb = fmaf( u, c, 63.5f);

    const uint4* __restrict__ vol4 = (const uint4*)volh;  // 16B units: column = 16 units

    float acc[8];
#pragma unroll
    for (int k = 0; k < 8; ++k) acc[k] = 0.f;

    const int spseg = NSTEPS / gridDim.z;
    const int i0 = blockIdx.z * spseg;
    const int i1 = i0 + spseg;

    for (int i = i0; i < i1; ++i) {
        const float t  = fmaf((float)i + 0.5f, DT, -T_HALF);
        const float xi = fmaf(t, c, xb);
        const float yi = fmaf(t, s, yb);

        const float fx0f = floorf(xi);
        const float fy0f = floorf(yi);
        const int x0 = (int)fx0f;
        const int y0 = (int)fy0f;
        const float fx = xi - fx0f;
        const float fy = yi - fy0f;
        const int x1 = x0 + 1;
        const int y1 = y0 + 1;

        const float wx0 = (x0 >= 0 && x0 < W_N) ? (1.f - fx) : 0.f;
        const float wx1 = (x1 >= 0 && x1 < W_N) ? fx : 0.f;
        const float wy0 = (y0 >= 0 && y0 < H_N) ? (1.f - fy) : 0.f;
        const float wy1 = (y1 >= 0 && y1 < H_N) ? fy : 0.f;

        if ((wx0 + wx1) == 0.f || (wy0 + wy1) == 0.f) continue;

        const int cx0 = min(max(x0, 0), W_N - 1);
        const int cx1 = min(max(x1, 0), W_N - 1);
        const int cy0 = min(max(y0, 0), H_N - 1);
        const int cy1 = min(max(y1, 0), H_N - 1);

        const int i00 = (((cx0 << 7) + cy0) << 4) + zo;
        const int i01 = (((cx1 << 7) + cy0) << 4) + zo;
        const int i10 = (((cx0 << 7) + cy1) << 4) + zo;
        const int i11 = (((cx1 << 7) + cy1) << 4) + zo;

        const uint4 q00 = vol4[i00];
        const uint4 q01 = vol4[i01];
        const uint4 q10 = vol4[i10];
        const uint4 q11 = vol4[i11];

        const __half2 w00 = __float2half2_rn(wx0 * wy0);
        const __half2 w01 = __float2half2_rn(wx1 * wy0);
        const __half2 w10 = __float2half2_rn(wx0 * wy1);
        const __half2 w11 = __float2half2_rn(wx1 * wy1);

        const __half2* h00 = (const __half2*)&q00;
        const __half2* h01 = (const __half2*)&q01;
        const __half2* h10 = (const __half2*)&q10;
        const __half2* h11 = (const __half2*)&q11;

#pragma unroll
        for (int j = 0; j < 4; ++j) {
            __half2 p = __hmul2(w00, h00[j]);
            p = __hfma2(w01, h01[j], p);
            p = __hfma2(w10, h10[j], p);
            p = __hfma2(w11, h11[j], p);
            const float2 f = __half22float2(p);
            acc[2 * j]     += f.x;
            acc[2 * j + 1] += f.y;
        }
    }

    float* op = dst + (size_t)blockIdx.z * SINO + ((size_t)u_i * A_N + a) * V_N + 8 * zo;
    *(float4*)(op)     = make_float4(acc[0] * scale, acc[1] * scale, acc[2] * scale, acc[3] * scale);
    *(float4*)(op + 4) = make_float4(acc[4] * scale, acc[5] * scale, acc[6] * scale, acc[7] * scale);
}

// ---- reduce: out = (p0+p1+p2+p3) * DT ----
__global__ __launch_bounds__(256) void reduce_segs(
    const float4* __restrict__ p, float4* __restrict__ out)
{
    const size_t i = (size_t)blockIdx.x * 256 + threadIdx.x;  // SINO/4 threads
    const size_t q = SINO / 4;
    const float4 a = p[i];
    const float4 b = p[i + q];
    const float4 c = p[i + 2 * q];
    const float4 d = p[i + 3 * q];
    out[i] = make_float4((a.x + b.x + c.x + d.x) * DT,
                         (a.y + b.y + c.y + d.y) * DT,
                         (a.z + b.z + c.z + d.z) * DT,
                         (a.w + b.w + c.w + d.w) * DT);
}

// ---- fallback: fp32 volume (only if ws too small for f16 copy) ----
__global__ __launch_bounds__(256) void joseph_fwd_f32(
    const float* __restrict__ vol,
    const float* __restrict__ angles,
    float* __restrict__ out)
{
    const int zo  = threadIdx.x & 15;
    const int r   = threadIdx.x >> 4;
    const int u_i = blockIdx.x * RAYS_PER_BLOCK + r;
    const int a   = blockIdx.y;

    const float ang = angles[a];
    const float c = cosf(ang);
    const float s = sinf(ang);
    const float u = (float)u_i - 63.5f;
    const float xb = fmaf(-u, s, 63.5f);
    const float yb = fmaf( u, c, 63.5f);

    const float* volz = vol + 8 * zo;
    float4 accA = make_float4(0.f, 0.f, 0.f, 0.f);
    float4 accB = make_float4(0.f, 0.f, 0.f, 0.f);

    for (int i = 0; i < NSTEPS; ++i) {
        const float t  = fmaf((float)i + 0.5f, DT, -T_HALF);
        const float xi = fmaf(t, c, xb);
        const float yi = fmaf(t, s, yb);
        const float fx0f = floorf(xi);
        const float fy0f = floorf(yi);
        const int x0 = (int)fx0f;
        const int y0 = (int)fy0f;
        const float fx = xi - fx0f;
        const float fy = yi - fy0f;
        const int x1 = x0 + 1;
        const int y1 = y0 + 1;
        const float wx0 = (x0 >= 0 && x0 < W_N) ? (1.f - fx) : 0.f;
        const float wx1 = (x1 >= 0 && x1 < W_N) ? fx : 0.f;
        const float wy0 = (y0 >= 0 && y0 < H_N) ? (1.f - fy) : 0.f;
        const float wy1 = (y1 >= 0 && y1 < H_N) ? fy : 0.f;
        if ((wx0 + wx1) == 0.f || (wy0 + wy1) == 0.f) continue;
        const int cx0 = min(max(x0, 0), W_N - 1);
        const int cx1 = min(max(x1, 0), W_N - 1);
        const int cy0 = min(max(y0, 0), H_N - 1);
        const int cy1 = min(max(y1, 0), H_N - 1);
        const float* p00 = volz + ((cx0 * H_N + cy0) << 7);
        const float* p01 = volz + ((cx1 * H_N + cy0) << 7);
        const float* p10 = volz + ((cx0 * H_N + cy1) << 7);
        const float* p11 = volz + ((cx1 * H_N + cy1) << 7);
        const float4 v00a = *(const float4*)(p00);
        const float4 v00b = *(const float4*)(p00 + 4);
        const float4 v01a = *(const float4*)(p01);
        const float4 v01b = *(const float4*)(p01 + 4);
        const float4 v10a = *(const float4*)(p10);
        const float4 v10b = *(const float4*)(p10 + 4);
        const float4 v11a = *(const float4*)(p11);
        const float4 v11b = *(const float4*)(p11 + 4);
        const float w00 = wx0 * wy0, w01 = wx1 * wy0, w10 = wx0 * wy1, w11 = wx1 * wy1;
        accA.x = fmaf(w00, v00a.x, fmaf(w01, v01a.x, fmaf(w10, v10a.x, fmaf(w11, v11a.x, accA.x))));
        accA.y = fmaf(w00, v00a.y, fmaf(w01, v01a.y, fmaf(w10, v10a.y, fmaf(w11, v11a.y, accA.y))));
        accA.z = fmaf(w00, v00a.z, fmaf(w01, v01a.z, fmaf(w10, v10a.z, fmaf(w11, v11a.z, accA.z))));
        accA.w = fmaf(w00, v00a.w, fmaf(w01, v01a.w, fmaf(w10, v10a.w, fmaf(w11, v11a.w, accA.w))));
        accB.x = fmaf(w00, v00b.x, fmaf(w01, v01b.x, fmaf(w10, v10b.x, fmaf(w11, v11b.x, accB.x))));
        accB.y = fmaf(w00, v00b.y, fmaf(w01, v01b.y, fmaf(w10, v10b.y, fmaf(w11, v11b.y, accB.y))));
        accB.z = fmaf(w00, v00b.z, fmaf(w01, v01b.z, fmaf(w10, v10b.z, fmaf(w11, v11b.z, accB.z))));
        accB.w = fmaf(w00, v00b.w, fmaf(w01, v01b.w, fmaf(w10, v10b.w, fmaf(w11, v11b.w, accB.w))));
    }

    float* op = out + ((size_t)u_i * A_N + a) * V_N + 8 * zo;
    *(float4*)(op)     = make_float4(accA.x * DT, accA.y * DT, accA.z * DT, accA.w * DT);
    *(float4*)(op + 4) = make_float4(accB.x * DT, accB.y * DT, accB.z * DT, accB.w * DT);
}

extern "C" void kernel_launch(void* const* d_in, const int* in_sizes, int n_in,
                              void* d_out, int out_size, void* d_ws, size_t ws_size,
                              hipStream_t stream) {
    const float* vol    = (const float*)d_in[0];
    const float* angles = (const float*)d_in[1];
    float* out          = (float*)d_out;

    const size_t need_full = VOLH_BYTES + SEGS * SINO * sizeof(float);  // 4 MB + 25.2 MB

    if (ws_size >= VOLH_BYTES) {
        unsigned int* volh = (unsigned int*)d_ws;
        hipLaunchKernelGGL(vol_to_f16, dim3(VOL_ELEMS / 8 / 256), dim3(256), 0, stream,
                           vol, volh);
        if (ws_size >= need_full) {
            float* partial = (float*)((char*)d_ws + VOLH_BYTES);
            dim3 grid(U_N / RAYS_PER_BLOCK, A_N, SEGS);   // 8 x 96 x 4 = 3072 blocks
            hipLaunchKernelGGL(joseph_fwd_f16, grid, dim3(256), 0, stream,
                               (const unsigned short*)volh, angles, partial, 1.0f);
            hipLaunchKernelGGL(reduce_segs, dim3(SINO / 4 / 256), dim3(256), 0, stream,
                               (const float4*)partial, (float4*)out);
        } else {
            dim3 grid(U_N / RAYS_PER_BLOCK, A_N, 1);
            hipLaunchKernelGGL(joseph_fwd_f16, grid, dim3(256), 0, stream,
                               (const unsigned short*)volh, angles, out, DT);
        }
    } else {
        dim3 grid(U_N / RAYS_PER_BLOCK, A_N);
        hipLaunchKernelGGL(joseph_fwd_f32, grid, dim3(256), 0, stream, vol, angles, out);
    }
}

// Round 7
// 114.004 us; speedup vs baseline: 2.0404x; 1.0432x over previous
//
#include <hip/hip_runtime.h>
#include <hip/hip_fp16.h>

namespace {
constexpr int A_N = 96;
constexpr int U_N = 128;
constexpr int V_N = 128;
constexpr int W_N = 128;
constexpr int H_N = 128;
constexpr int NSTEPS = 128;
constexpr float T_HALF = 89.80256121069154f;
constexpr float DT = 1.4031650189170554f;   // 2*T/NSTEPS
constexpr float INV_DT = 1.0f / DT;
constexpr int RAYS_PER_BLOCK = 16;          // 16 lanes/ray (8 z each), 16 rays/block
constexpr int SEGS = 4;
constexpr int SEG_STEPS = NSTEPS / SEGS;    // 32
constexpr size_t VOL_ELEMS = (size_t)W_N * H_N * V_N;             // 2M
constexpr size_t VOLH_BYTES = VOL_ELEMS * sizeof(unsigned short); // 4 MB
constexpr size_t SINO = (size_t)U_N * A_N * V_N;                  // 1.57M floats
constexpr int TAB_STRIDE = SEG_STEPS + 1;   // 33: LDS bank-conflict padding
}

// ---- bit-cast helpers (no __half2_as_uint in HIP) ----
__device__ __forceinline__ unsigned int h2u(__half2 h) {
    union { __half2 h; unsigned int u; } v; v.h = h; return v.u;
}
__device__ __forceinline__ __half2 u2h(unsigned int u) {
    union { unsigned int u; __half2 h; } v; v.u = u; return v.h;
}

// ---- pre-pass: fp32 volume -> f16 (rte), 8 values/thread ----
__device__ __forceinline__ unsigned int packh2(float a, float b) {
    return (unsigned int)__half_as_ushort(__float2half_rn(a)) |
           ((unsigned int)__half_as_ushort(__float2half_rn(b)) << 16);
}

__global__ __launch_bounds__(256) void vol_to_f16(
    const float* __restrict__ vol, unsigned int* __restrict__ volh)
{
    const size_t i = (size_t)blockIdx.x * 256 + threadIdx.x;
    const float4 f0 = *(const float4*)(vol + 8 * i);
    const float4 f1 = *(const float4*)(vol + 8 * i + 4);
    uint4 o;
    o.x = packh2(f0.x, f0.y);
    o.y = packh2(f0.z, f0.w);
    o.z = packh2(f1.x, f1.y);
    o.w = packh2(f1.z, f1.w);
    *(uint4*)(volh + 4 * i) = o;
}

// ---- main projector: per-block LDS geometry table + f16 volume ----
__global__ __launch_bounds__(256) void joseph_fwd_tab(
    const unsigned short* __restrict__ volh,
    const float* __restrict__ angles,
    float* __restrict__ dst, float scale)
{
    __shared__ uint4 s_offs[RAYS_PER_BLOCK * TAB_STRIDE];  // 4 column byte-offsets
    __shared__ uint4 s_wts [RAYS_PER_BLOCK * TAB_STRIDE];  // 4 dup'd half2 weights

    const int a  = blockIdx.y;
    const int i0 = blockIdx.z * SEG_STEPS;

    const float ang = angles[a];
    const float cv = cosf(ang);
    const float sv = sinf(ang);

    // ---- build the 16-ray x 32-step geometry table (2 entries/thread) ----
    for (int e = threadIdx.x; e < RAYS_PER_BLOCK * SEG_STEPS; e += 256) {
        const int r = e >> 5;           // ray in block
        const int k = e & 31;           // step in segment
        const float up = (float)(blockIdx.x * RAYS_PER_BLOCK + r) - 63.5f;
        const float xb = fmaf(-up, sv, 63.5f);
        const float yb = fmaf( up, cv, 63.5f);
        const float t  = fmaf((float)(i0 + k) + 0.5f, DT, -T_HALF);
        const float xi = fmaf(t, cv, xb);
        const float yi = fmaf(t, sv, yb);

        const float fx0f = floorf(xi);
        const float fy0f = floorf(yi);
        const int x0 = (int)fx0f;
        const int y0 = (int)fy0f;
        const float fx = xi - fx0f;
        const float fy = yi - fy0f;
        const int x1 = x0 + 1;
        const int y1 = y0 + 1;

        const float wx0 = (x0 >= 0 && x0 < W_N) ? (1.f - fx) : 0.f;
        const float wx1 = (x1 >= 0 && x1 < W_N) ? fx : 0.f;
        const float wy0 = (y0 >= 0 && y0 < H_N) ? (1.f - fy) : 0.f;
        const float wy1 = (y1 >= 0 && y1 < H_N) ? fy : 0.f;

        const int cx0 = min(max(x0, 0), W_N - 1);
        const int cx1 = min(max(x1, 0), W_N - 1);
        const int cy0 = min(max(y0, 0), H_N - 1);
        const int cy1 = min(max(y1, 0), H_N - 1);

        // column byte offsets (f16: 128 z * 2B = 256 B per (x,y) column)
        uint4 off;
        off.x = (unsigned)(((cx0 << 7) + cy0) << 8);
        off.y = (unsigned)(((cx1 << 7) + cy0) << 8);
        off.z = (unsigned)(((cx0 << 7) + cy1) << 8);
        off.w = (unsigned)(((cx1 << 7) + cy1) << 8);

        uint4 w;
        w.x = h2u(__float2half2_rn(wx0 * wy0));
        w.y = h2u(__float2half2_rn(wx1 * wy0));
        w.z = h2u(__float2half2_rn(wx0 * wy1));
        w.w = h2u(__float2half2_rn(wx1 * wy1));

        const int idx = r * TAB_STRIDE + k;
        s_offs[idx] = off;
        s_wts[idx]  = w;
    }
    __syncthreads();

    // ---- per-thread ray setup ----
    const int zo  = threadIdx.x & 15;        // 16 z-groups of 8
    const int r   = threadIdx.x >> 4;        // ray in block
    const int u_i = blockIdx.x * RAYS_PER_BLOCK + r;
    const unsigned lane16 = (unsigned)(zo << 4);  // byte offset within column
    const char* __restrict__ volc = (const char*)volh;

    const float up = (float)u_i - 63.5f;
    const float xb = fmaf(-up, sv, 63.5f);
    const float yb = fmaf( up, cv, 63.5f);

    // valid-step range: xi,yi must lie in (-1, 128); interval is contiguous
    const int i1 = i0 + SEG_STEPS;
    float tlo = -2.f * T_HALF, thi = 2.f * T_HALF;
    if (fabsf(cv) > 1e-6f) {
        const float ta = (-1.f - xb) / cv, tb = (128.f - xb) / cv;
        tlo = fmaxf(tlo, fminf(ta, tb));
        thi = fminf(thi, fmaxf(ta, tb));
    } else if (xb <= -1.f || xb >= 128.f) { thi = tlo - 1.f; }
    if (fabsf(sv) > 1e-6f) {
        const float ta = (-1.f - yb) / sv, tb = (128.f - yb) / sv;
        tlo = fmaxf(tlo, fminf(ta, tb));
        thi = fminf(thi, fmaxf(ta, tb));
    } else if (yb <= -1.f || yb >= 128.f) { thi = tlo - 1.f; }
    const int ilo = (int)floorf(fmaf(tlo + T_HALF, INV_DT, -0.5f)) - 1;
    const int ihi = (int)ceilf (fmaf(thi + T_HALF, INV_DT, -0.5f)) + 1;
    int lo = min(max(ilo, i0), i1);
    int hi = min(max(ihi + 1, i0), i1);
    if (hi < lo) hi = lo;
    const int lo8 = i0 + ((lo - i0) & ~7);        // 8-aligned (OOB entries have
    const int hi8 = i0 + ((hi - i0 + 7) & ~7);    //  zero weights -> safe pad)

    float accf[8];
#pragma unroll
    for (int k = 0; k < 8; ++k) accf[k] = 0.f;

    const __half2 hz = __float2half2_rn(0.f);

    for (int i = lo8; i < hi8; i += 8) {
        __half2 a0 = hz, a1 = hz, a2 = hz, a3 = hz;
        const int eb = r * TAB_STRIDE + (i - i0);
#pragma unroll
        for (int k = 0; k < 8; ++k) {
            const uint4 off = s_offs[eb + k];
            const uint4 w   = s_wts [eb + k];

            const uint4 q00 = *(const uint4*)(volc + (off.x + lane16));
            const uint4 q01 = *(const uint4*)(volc + (off.y + lane16));
            const uint4 q10 = *(const uint4*)(volc + (off.z + lane16));
            const uint4 q11 = *(const uint4*)(volc + (off.w + lane16));

            const __half2 w00 = u2h(w.x);
            const __half2 w01 = u2h(w.y);
            const __half2 w10 = u2h(w.z);
            const __half2 w11 = u2h(w.w);

            const __half2* h00 = (const __half2*)&q00;
            const __half2* h01 = (const __half2*)&q01;
            const __half2* h10 = (const __half2*)&q10;
            const __half2* h11 = (const __half2*)&q11;

            a0 = __hfma2(w00, h00[0], __hfma2(w01, h01[0], __hfma2(w10, h10[0], __hfma2(w11, h11[0], a0))));
            a1 = __hfma2(w00, h00[1], __hfma2(w01, h01[1], __hfma2(w10, h10[1], __hfma2(w11, h11[1], a1))));
            a2 = __hfma2(w00, h00[2], __hfma2(w01, h01[2], __hfma2(w10, h10[2], __hfma2(w11, h11[2], a2))));
            a3 = __hfma2(w00, h00[3], __hfma2(w01, h01[3], __hfma2(w10, h10[3], __hfma2(w11, h11[3], a3))));
        }
        accf[0] += __low2float(a0); accf[1] += __high2float(a0);
        accf[2] += __low2float(a1); accf[3] += __high2float(a1);
        accf[4] += __low2float(a2); accf[5] += __high2float(a2);
        accf[6] += __low2float(a3); accf[7] += __high2float(a3);
    }

    float* op = dst + (size_t)blockIdx.z * SINO + ((size_t)u_i * A_N + a) * V_N + 8 * zo;
    *(float4*)(op)     = make_float4(accf[0] * scale, accf[1] * scale, accf[2] * scale, accf[3] * scale);
    *(float4*)(op + 4) = make_float4(accf[4] * scale, accf[5] * scale, accf[6] * scale, accf[7] * scale);
}

// ---- reduce: out = (p0+p1+p2+p3) * DT ----
__global__ __launch_bounds__(256) void reduce_segs(
    const float4* __restrict__ p, float4* __restrict__ out)
{
    const size_t i = (size_t)blockIdx.x * 256 + threadIdx.x;  // SINO/4 threads
    const size_t q = SINO / 4;
    const float4 a = p[i];
    const float4 b = p[i + q];
    const float4 c = p[i + 2 * q];
    const float4 d = p[i + 3 * q];
    out[i] = make_float4((a.x + b.x + c.x + d.x) * DT,
                         (a.y + b.y + c.y + d.y) * DT,
                         (a.z + b.z + c.z + d.z) * DT,
                         (a.w + b.w + c.w + d.w) * DT);
}

// ---- fallback: fp32 volume, no workspace needed (R2 structure) ----
__global__ __launch_bounds__(256) void joseph_fwd_f32(
    const float* __restrict__ vol,
    const float* __restrict__ angles,
    float* __restrict__ out)
{
    const int zo  = threadIdx.x & 15;
    const int r   = threadIdx.x >> 4;
    const int u_i = blockIdx.x * RAYS_PER_BLOCK + r;
    const int a   = blockIdx.y;

    const float ang = angles[a];
    const float c = cosf(ang);
    const float s = sinf(ang);
    const float u = (float)u_i - 63.5f;
    const float xb = fmaf(-u, s, 63.5f);
    const float yb = fmaf( u, c, 63.5f);

    const float* volz = vol + 8 * zo;
    float4 accA = make_float4(0.f, 0.f, 0.f, 0.f);
    float4 accB = make_float4(0.f, 0.f, 0.f, 0.f);

    for (int i = 0; i < NSTEPS; ++i) {
        const float t  = fmaf((float)i + 0.5f, DT, -T_HALF);
        const float xi = fmaf(t, c, xb);
        const float yi = fmaf(t, s, yb);
        const float fx0f = floorf(xi);
        const float fy0f = floorf(yi);
        const int x0 = (int)fx0f;
        const int y0 = (int)fy0f;
        const float fx = xi - fx0f;
        const float fy = yi - fy0f;
        const int x1 = x0 + 1;
        const int y1 = y0 + 1;
        const float wx0 = (x0 >= 0 && x0 < W_N) ? (1.f - fx) : 0.f;
        const float wx1 = (x1 >= 0 && x1 < W_N) ? fx : 0.f;
        const float wy0 = (y0 >= 0 && y0 < H_N) ? (1.f - fy) : 0.f;
        const float wy1 = (y1 >= 0 && y1 < H_N) ? fy : 0.f;
        if ((wx0 + wx1) == 0.f || (wy0 + wy1) == 0.f) continue;
        const int cx0 = min(max(x0, 0), W_N - 1);
        const int cx1 = min(max(x1, 0), W_N - 1);
        const int cy0 = min(max(y0, 0), H_N - 1);
        const int cy1 = min(max(y1, 0), H_N - 1);
        const float* p00 = volz + ((cx0 * H_N + cy0) << 7);
        const float* p01 = volz + ((cx1 * H_N + cy0) << 7);
        const float* p10 = volz + ((cx0 * H_N + cy1) << 7);
        const float* p11 = volz + ((cx1 * H_N + cy1) << 7);
        const float4 v00a = *(const float4*)(p00);
        const float4 v00b = *(const float4*)(p00 + 4);
        const float4 v01a = *(const float4*)(p01);
        const float4 v01b = *(const float4*)(p01 + 4);
        const float4 v10a = *(const float4*)(p10);
        const float4 v10b = *(const float4*)(p10 + 4);
        const float4 v11a = *(const float4*)(p11);
        const float4 v11b = *(const float4*)(p11 + 4);
        const float w00 = wx0 * wy0, w01 = wx1 * wy0, w10 = wx0 * wy1, w11 = wx1 * wy1;
        accA.x = fmaf(w00, v00a.x, fmaf(w01, v01a.x, fmaf(w10, v10a.x, fmaf(w11, v11a.x, accA.x))));
        accA.y = fmaf(w00, v00a.y, fmaf(w01, v01a.y, fmaf(w10, v10a.y, fmaf(w11, v11a.y, accA.y))));
        accA.z = fmaf(w00, v00a.z, fmaf(w01, v01a.z, fmaf(w10, v10a.z, fmaf(w11, v11a.z, accA.z))));
        accA.w = fmaf(w00, v00a.w, fmaf(w01, v01a.w, fmaf(w10, v10a.w, fmaf(w11, v11a.w, accA.w))));
        accB.x = fmaf(w00, v00b.x, fmaf(w01, v01b.x, fmaf(w10, v10b.x, fmaf(w11, v11b.x, accB.x))));
        accB.y = fmaf(w00, v00b.y, fmaf(w01, v01b.y, fmaf(w10, v10b.y, fmaf(w11, v11b.y, accB.y))));
        accB.z = fmaf(w00, v00b.z, fmaf(w01, v01b.z, fmaf(w10, v10b.z, fmaf(w11, v11b.z, accB.z))));
        accB.w = fmaf(w00, v00b.w, fmaf(w01, v01b.w, fmaf(w10, v10b.w, fmaf(w11, v11b.w, accB.w))));
    }

    float* op = out + ((size_t)u_i * A_N + a) * V_N + 8 * zo;
    *(float4*)(op)     = make_float4(accA.x * DT, accA.y * DT, accA.z * DT, accA.w * DT);
    *(float4*)(op + 4) = make_float4(accB.x * DT, accB.y * DT, accB.z * DT, accB.w * DT);
}

extern "C" void kernel_launch(void* const* d_in, const int* in_sizes, int n_in,
                              void* d_out, int out_size, void* d_ws, size_t ws_size,
                              hipStream_t stream) {
    const float* vol    = (const float*)d_in[0];
    const float* angles = (const float*)d_in[1];
    float* out          = (float*)d_out;

    const size_t need_full = VOLH_BYTES + SEGS * SINO * sizeof(float);  // 4 MB + 25.2 MB

    if (ws_size >= VOLH_BYTES) {
        unsigned int* volh = (unsigned int*)d_ws;
        hipLaunchKernelGGL(vol_to_f16, dim3(VOL_ELEMS / 8 / 256), dim3(256), 0, stream,
                           vol, volh);
        if (ws_size >= need_full) {
            float* partial = (float*)((char*)d_ws + VOLH_BYTES);
            dim3 grid(U_N / RAYS_PER_BLOCK, A_N, SEGS);   // 8 x 96 x 4 = 3072 blocks
            hipLaunchKernelGGL(joseph_fwd_tab, grid, dim3(256), 0, stream,
                               (const unsigned short*)volh, angles, partial, 1.0f);
            hipLaunchKernelGGL(reduce_segs, dim3(SINO / 4 / 256), dim3(256), 0, stream,
                               (const float4*)partial, (float4*)out);
        } else {
            dim3 grid(U_N / RAYS_PER_BLOCK, A_N, 1);
            hipLaunchKernelGGL(joseph_fwd_tab, grid, dim3(256), 0, stream,
                               (const unsigned short*)volh, angles, out, DT);
        }
    } else {
        dim3 grid(U_N / RAYS_PER_BLOCK, A_N);
        hipLaunchKernelGGL(joseph_fwd_f32, grid, dim3(256), 0, stream, vol, angles, out);
    }
}